// Round 15
// baseline (3693.507 us; speedup 1.0000x reference)
//
#include <hip/hip_runtime.h>
#include <hip/hip_cooperative_groups.h>
#include <cmath>

namespace cg = cooperative_groups;

#define NALL 3072
#define NF   3056
#define NT   3056
#define NC4  764          // NT/4
#define RPB  4            // rows per block (764 blocks: ~3 blocks/CU)
#define NBLK (NF/RPB)     // 764 blocks
#define CB   (NT/16)      // 191 phase-2 reducer blocks
#define SPLIT 32          // fallback colsum slices
#define RPS  ((NBLK + SPLIT - 1) / SPLIT)
#define TPB  256
#define CGRP ((NT + TPB - 1) / TPB)
#define LRc  0.1f
#define AEPS 1e-8f
#define OEPS 0.1f
#define ITERS 100

__device__ __forceinline__ float sigf(float x) {
    return 1.0f / (1.0f + __expf(-x));
}

// ---- bf16 helpers ----
__device__ __forceinline__ unsigned int pkbf(float x) {
    unsigned int t = __float_as_uint(x);
    return (t + 0x7FFFu + ((t >> 16) & 1u)) >> 16;
}
__device__ __forceinline__ float4 ld_bf4(const unsigned short* p) {
    uint2 u = *(const uint2*)p;
    float4 r;
    r.x = __uint_as_float(u.x << 16);
    r.y = __uint_as_float(u.x & 0xFFFF0000u);
    r.z = __uint_as_float(u.y << 16);
    r.w = __uint_as_float(u.y & 0xFFFF0000u);
    return r;
}
__device__ __forceinline__ void st_bf4(unsigned short* p, float4 v) {
    uint2 u;
    u.x = pkbf(v.x) | (pkbf(v.y) << 16);
    u.y = pkbf(v.z) | (pkbf(v.w) << 16);
    *(uint2*)p = u;
}
// 8-element (16B) bf16 load/store
__device__ __forceinline__ void ld_bf8(const unsigned short* p, float* o) {
    uint4 u = *(const uint4*)p;
    o[0]=__uint_as_float(u.x<<16); o[1]=__uint_as_float(u.x&0xFFFF0000u);
    o[2]=__uint_as_float(u.y<<16); o[3]=__uint_as_float(u.y&0xFFFF0000u);
    o[4]=__uint_as_float(u.z<<16); o[5]=__uint_as_float(u.z&0xFFFF0000u);
    o[6]=__uint_as_float(u.w<<16); o[7]=__uint_as_float(u.w&0xFFFF0000u);
}
__device__ __forceinline__ void st_bf8(unsigned short* p, const float* v) {
    uint4 u;
    u.x = pkbf(v[0]) | (pkbf(v[1])<<16);
    u.y = pkbf(v[2]) | (pkbf(v[3])<<16);
    u.z = pkbf(v[4]) | (pkbf(v[5])<<16);
    u.w = pkbf(v[6]) | (pkbf(v[7])<<16);
    *(uint4*)p = u;
}
__device__ __forceinline__ void load8_gl(const float* GL_init, const unsigned short* GLbf,
                                         bool first, size_t e, float* o) {
    if (first) {
        float4 u0 = *(const float4*)(GL_init + e);
        float4 u1 = *(const float4*)(GL_init + e + 4);
        o[0]=u0.x; o[1]=u0.y; o[2]=u0.z; o[3]=u0.w;
        o[4]=u1.x; o[5]=u1.y; o[6]=u1.z; o[7]=u1.w;
    } else {
        ld_bf8(GLbf + e, o);
    }
}

// ---------------- one-time cast of A[:NF, 16:] block to bf16 ----------------
__global__ void __launch_bounds__(TPB)
castA_kernel(const float* __restrict__ A, unsigned short* __restrict__ Abf)
{
    const int tid = threadIdx.x;
    const bool ok2 = tid < (NC4 - 512);
    const int i = blockIdx.x;
    const size_t abase = (size_t)i * NALL + 16;
    const size_t obase = (size_t)i * NT;
    #pragma unroll
    for (int k = 0; k < 3; ++k) {
        if (k == 2 && !ok2) continue;
        const int c4 = tid + 256*k;
        float4 a = *(const float4*)(A + abase + 4*c4);
        st_bf4(Abf + obase + 4*c4, a);
    }
}

// ---------------- cooperative mega-kernel: 2 grid.syncs, 3 block-barriers per iter ----------------
__global__ void __launch_bounds__(TPB, 4)
mega_kernel(const float* __restrict__ A, const float* __restrict__ tau_init,
            const float* __restrict__ GL_init,
            unsigned short* __restrict__ GLbf, unsigned short* __restrict__ mG,
            unsigned short* __restrict__ vG, const unsigned short* __restrict__ Abf,
            float* __restrict__ tau_g,  /* [2][NALL] */
            float* __restrict__ mt_g,   /* [2][NALL] */
            float* __restrict__ vt_g,   /* [2][NALL] */
            float* __restrict__ Srow_g, /* [2][NALL] */
            float* __restrict__ Pcol,   /* [NBLK][NT] */
            float* __restrict__ Gcol,   /* [NT] */
            float* __restrict__ out)
{
    cg::grid_group grid = cg::this_grid();
    __shared__ float tau_s[NALL];   // 12 KB
    __shared__ float redp[16];      // row products (4 rows x 4 waves)
    __shared__ float reds[16];      // row sums
    __shared__ float redc[64];
    const int tid  = threadIdx.x;
    const int lane = tid & 63;
    const int wv   = tid >> 6;
    const bool ok2 = tid < 126;     // chunk1 (elements 2048+8t..+7) valid
    const int b    = blockIdx.x;
    const float c1 = 0.5f / (float)NF;
    const float c2 = 0.5f / ((float)NF * (float)NT);
    const float ct = 1.0f / ((float)NF * (float)NT);

    double b1p = 1.0, b2p = 1.0;
    for (int it = 0; it < ITERS; ++it) {
        const float bc1t = (it > 0) ? (float)(1.0/(1.0 - b1p)) : 0.f;
        const float bc2t = (it > 0) ? (float)(1.0/(1.0 - b2p)) : 0.f;
        b1p *= 0.9; b2p *= 0.999;
        const float bc1i = (float)(1.0/(1.0 - b1p));
        const float bc2i = (float)(1.0/(1.0 - b2p));
        const int rp = (it - 1) & 1, wp = it & 1;
        const bool first = (it == 0);

        // ======== phase 1a: tau Adam update (redundant per block) into LDS ========
        #pragma unroll
        for (int j = 0; j < 3; ++j) {
            const int q = tid + 256*j;
            float4 tnew, m2q = make_float4(0.f,0.f,0.f,0.f), v2q = m2q;
            if (it == 0) {
                tnew = ((const float4*)tau_init)[q];
            } else {
                const float4 t0 = ((const float4*)(tau_g + rp*NALL))[q];
                float4 sr = make_float4(0.f,0.f,0.f,0.f), gc = sr, m0 = sr, v0 = sr;
                if (q < NF/4) sr = ((const float4*)(Srow_g + rp*NALL))[q];
                if (q >= 4)   gc = ((const float4*)Gcol)[q - 4];
                if (it > 1) { m0 = ((const float4*)(mt_g + rp*NALL))[q];
                              v0 = ((const float4*)(vt_g + rp*NALL))[q]; }
                #define TADAM(F) { \
                    const float g = (sr.F - gc.F) * ct; \
                    const float m2 = fmaf(0.9f, m0.F, 0.1f*g); \
                    const float v2 = fmaf(0.999f, v0.F, 0.001f*g*g); \
                    const float den = __fsqrt_rn(v2 * bc2t) + AEPS; \
                    tnew.F = t0.F - LRc * (m2 * bc1t) / den; \
                    m2q.F = m2; v2q.F = v2; }
                TADAM(x) TADAM(y) TADAM(z) TADAM(w)
                #undef TADAM
            }
            ((float4*)tau_s)[q] = tnew;
            if (b == tid) {
                ((float4*)(tau_g + wp*NALL))[q] = tnew;
                if (it > 0) {
                    ((float4*)(mt_g + wp*NALL))[q] = m2q;
                    ((float4*)(vt_g + wp*NALL))[q] = v2q;
                }
            }
        }
        __syncthreads();   // barrier 1: tau_s ready

        // ======== product pass: no barriers (rows independent, wave shuffle reduce) ========
        for (int rr = 0; rr < RPB; ++rr) {
            const size_t e0 = (size_t)(b * RPB + rr) * NT;
            float pl = 1.0f;
            #pragma unroll
            for (int ch = 0; ch < 2; ++ch) {
                if (ch == 1 && !ok2) break;
                const size_t e = e0 + 8*tid + (ch ? 2048 : 0);
                float gl8[8], a8[8];
                load8_gl(GL_init, GLbf, first, e, gl8);
                ld_bf8(Abf + e, a8);
                #pragma unroll
                for (int u = 0; u < 8; ++u)
                    pl *= fmaf(-2.0f*a8[u], sigf(gl8[u]), 1.0f);
            }
            #pragma unroll
            for (int off = 1; off < 64; off <<= 1) pl *= __shfl_xor(pl, off, 64);
            if (lane == 0) redp[rr*4 + wv] = pl;
        }
        __syncthreads();   // barrier 2: products ready

        float p4[RPB];
        #pragma unroll
        for (int rr = 0; rr < RPB; ++rr)
            p4[rr] = (redp[rr*4+0]*redp[rr*4+1])*(redp[rr*4+2]*redp[rr*4+3]);

        // ======== update pass: no barriers; GL/A re-loads are L2-hot ========
        float cacc[16];
        #pragma unroll
        for (int u = 0; u < 16; ++u) cacc[u] = 0.0f;

        for (int rr = 0; rr < RPB; ++rr) {
            const int i = b * RPB + rr;
            const float tu = tau_s[i];
            const size_t e0 = (size_t)i * NT;
            const float p = p4[rr];
            const float c1pp = c1 * (p + 1.0f);
            const bool pzero = (p == 0.0f);
            float rowl = 0.0f;

            #pragma unroll
            for (int ch = 0; ch < 2; ++ch) {
                if (ch == 1 && !ok2) break;
                const int cb0 = 8*tid + (ch ? 2048 : 0);
                const size_t e = e0 + cb0;
                float gl8[8], a8[8], m8[8], v8[8];
                load8_gl(GL_init, GLbf, first, e, gl8);
                ld_bf8(Abf + e, a8);
                if (first) {
                    #pragma unroll
                    for (int u = 0; u < 8; ++u) { m8[u] = 0.0f; v8[u] = 0.0f; }
                } else {
                    ld_bf8(mG + e, m8);
                    ld_bf8(vG + e, v8);
                }
                const float4 tva = ((const float4*)tau_s)[(16 + cb0) >> 2];
                const float4 tvb = ((const float4*)tau_s)[((16 + cb0) >> 2) + 1];
                const float tvv[8] = {tva.x,tva.y,tva.z,tva.w,tvb.x,tvb.y,tvb.z,tvb.w};

                #pragma unroll
                for (int u = 0; u < 8; ++u) {
                    const float g = sigf(gl8[u]);
                    const float a = a8[u];
                    const float d = tu - tvv[u] + OEPS;
                    const float r = fmaxf(d, 0.0f);
                    float gg;
                    if (pzero) {
                        gg = (c2 * (r*r)) * (g * (1.0f - g));
                    } else {
                        const float f = fmaf(-2.0f*a, g, 1.0f);
                        const float po = (f != 0.0f) ? __fdividef(p, f) : 0.0f;
                        gg = fmaf(c2, r*r, c1pp * po * (-2.0f*a)) * (g * (1.0f - g));
                    }
                    const float m2 = fmaf(0.9f, m8[u], 0.1f*gg);
                    const float v2 = fmaf(0.999f, v8[u], 0.001f*gg*gg);
                    const float den = __fsqrt_rn(v2 * bc2i) + AEPS;
                    gl8[u] = gl8[u] - LRc * (m2 * bc1i) / den;
                    m8[u] = m2; v8[u] = v2;
                    const float w = g * r;
                    rowl += w;
                    cacc[ch*8 + u] += w;
                }
                st_bf8(GLbf + e, gl8);
                st_bf8(mG + e, m8);
                st_bf8(vG + e, v8);
            }
            #pragma unroll
            for (int off = 1; off < 64; off <<= 1) rowl += __shfl_xor(rowl, off, 64);
            if (lane == 0) reds[rr*4 + wv] = rowl;
        }
        __syncthreads();   // barrier 3: row sums ready
        if (tid < 4) {
            (Srow_g + wp*NALL)[b*RPB + tid] =
                (reds[tid*4+0] + reds[tid*4+1]) + (reds[tid*4+2] + reds[tid*4+3]);
        }

        // column partials (coalesced float4 stores)
        {
            float* pc = Pcol + (size_t)b * NT;
            *(float4*)(pc + 8*tid)     = make_float4(cacc[0],cacc[1],cacc[2],cacc[3]);
            *(float4*)(pc + 8*tid + 4) = make_float4(cacc[4],cacc[5],cacc[6],cacc[7]);
            if (ok2) {
                *(float4*)(pc + 2048 + 8*tid)     = make_float4(cacc[8],cacc[9],cacc[10],cacc[11]);
                *(float4*)(pc + 2048 + 8*tid + 4) = make_float4(cacc[12],cacc[13],cacc[14],cacc[15]);
            }
        }

        grid.sync();

        // ======== phase 2: coalesced column reduce (191 blocks, 16 cols each) ========
        if (b < CB) {
            const int col = 16*b + (tid & 15);
            float acc4[4] = {0.f,0.f,0.f,0.f};
            for (int rb = 0; rb < NBLK; rb += 64) {
                #pragma unroll
                for (int u = 0; u < 4; ++u) {
                    const int r = rb + 16*u + (tid >> 4);
                    if (r < NBLK) acc4[u] += Pcol[(size_t)r*NT + col];
                }
            }
            float acc = (acc4[0]+acc4[1]) + (acc4[2]+acc4[3]);
            acc += __shfl_xor(acc, 16, 64);
            acc += __shfl_xor(acc, 32, 64);
            if (lane < 16) redc[wv*16 + lane] = acc;
        }
        __syncthreads();
        if (b < CB && tid < 16) {
            Gcol[16*b + tid] = (redc[tid] + redc[16+tid]) + (redc[32+tid] + redc[48+tid]);
        }
        grid.sync();
    }

    // ======== final tau update (t = ITERS) into LDS ========
    {
        const float bc1t = (float)(1.0/(1.0 - b1p));
        const float bc2t = (float)(1.0/(1.0 - b2p));
        const int rp = (ITERS - 1) & 1;
        #pragma unroll
        for (int j = 0; j < 3; ++j) {
            const int q = tid + 256*j;
            const float4 t0 = ((const float4*)(tau_g + rp*NALL))[q];
            float4 sr = make_float4(0.f,0.f,0.f,0.f), gc = sr;
            if (q < NF/4) sr = ((const float4*)(Srow_g + rp*NALL))[q];
            if (q >= 4)   gc = ((const float4*)Gcol)[q - 4];
            const float4 m0 = ((const float4*)(mt_g + rp*NALL))[q];
            const float4 v0 = ((const float4*)(vt_g + rp*NALL))[q];
            float4 tnew;
            #define TADAM(F) { \
                const float g = (sr.F - gc.F) * ct; \
                const float m2 = fmaf(0.9f, m0.F, 0.1f*g); \
                const float v2 = fmaf(0.999f, v0.F, 0.001f*g*g); \
                const float den = __fsqrt_rn(v2 * bc2t) + AEPS; \
                tnew.F = t0.F - LRc * (m2 * bc1t) / den; }
            TADAM(x) TADAM(y) TADAM(z) TADAM(w)
            #undef TADAM
            ((float4*)tau_s)[q] = tnew;
        }
    }
    __syncthreads();

    // ======== final loss (original fp32 A, bf16 final GL, final tau in LDS) ========
    float lsum = 0.0f;
    {
        const bool okl = tid < (NC4 - 512);
        for (int rr = 0; rr < RPB; ++rr) {
            const int i = b * RPB + rr;
            const float tu = tau_s[i];
            const size_t g4base = (size_t)i * NC4;
            const size_t abase  = (size_t)i * NALL + 16;
            float pl = 1.0f, sl = 0.0f;
            #pragma unroll
            for (int k = 0; k < 3; ++k) {
                if (k == 2 && !okl) continue;
                const int c4 = tid + 256*k;
                float4 gl = ld_bf4(GLbf + 4*(g4base + c4));
                float4 a  = *(const float4*)(A + abase + 4*c4);
                float4 tvv = ((const float4*)tau_s)[4 + c4];
                #define LCOMP(FLD) { \
                    const float g = sigf(gl.FLD); \
                    pl *= fmaf(-2.0f*a.FLD, g, 1.0f); \
                    const float r = fmaxf(tu - tvv.FLD + OEPS, 0.0f); \
                    sl += g * r * r; }
                LCOMP(x) LCOMP(y) LCOMP(z) LCOMP(w)
                #undef LCOMP
            }
            float pw = pl, sw = sl;
            #pragma unroll
            for (int off = 1; off < 64; off <<= 1) {
                pw *= __shfl_xor(pw, off, 64);
                sw += __shfl_xor(sw, off, 64);
            }
            __syncthreads();
            if (lane == 0) { redp[wv] = pw; reds[wv] = sw; }
            __syncthreads();
            if (tid == 0) {
                const float p = redp[0]*redp[1]*redp[2]*redp[3];
                const float s = (reds[0]+reds[1]) + (reds[2]+reds[3]);
                lsum += 0.25f*(p+1.0f)*(p+1.0f)*(1.0f/(float)NF)
                      + 0.5f*s*(1.0f/((float)NF*(float)NT));
            }
        }
    }
    if (tid == 0) atomicAdd(out, lsum);
}

// ================= fallback path (round-13 structure, known-good) =================
template<bool FIRST>
__device__ __forceinline__ void step_rows_fb(
    int b, const float* __restrict__ GL_init,
    unsigned short* __restrict__ GLbf, unsigned short* __restrict__ mG,
    unsigned short* __restrict__ vG, const unsigned short* __restrict__ Abf,
    const float* __restrict__ tau, float* __restrict__ Srow,
    float* __restrict__ Pcol, float bc1i, float bc2i, float* red)
{
    const int tid  = threadIdx.x;
    const int lane = tid & 63;
    const int wv   = tid >> 6;
    const bool ok2 = tid < (NC4 - 512);
    const float c1 = 0.5f / (float)NF;
    const float c2 = 0.5f / ((float)NF * (float)NT);

    float4 tv[3];
    tv[0] = *(const float4*)(tau + 16 + 4 * tid);
    tv[1] = *(const float4*)(tau + 16 + 4 * (tid + 256));
    tv[2] = ok2 ? *(const float4*)(tau + 16 + 4 * (tid + 512)) : make_float4(0.f,0.f,0.f,0.f);

    float4 cacc[3];
    #pragma unroll
    for (int k = 0; k < 3; ++k) cacc[k] = make_float4(0.f,0.f,0.f,0.f);

    for (int rr = 0; rr < RPB; ++rr) {
        const int i = b * RPB + rr;
        const float tu = tau[i];
        const size_t g4base = (size_t)i * NC4;

        float4 gl[3], a4[3], m4[3], v4[3];
        #pragma unroll
        for (int k = 0; k < 3; ++k) {
            if (k == 2 && !ok2) continue;
            const int c4 = tid + 256*k;
            const size_t e = 4*(g4base + c4);
            gl[k] = FIRST ? ((const float4*)GL_init)[g4base + c4] : ld_bf4(GLbf + e);
            a4[k] = ld_bf4(Abf + e);
            if (FIRST) { m4[k] = make_float4(0.f,0.f,0.f,0.f); v4[k] = m4[k]; }
            else { m4[k] = ld_bf4(mG + e); v4[k] = ld_bf4(vG + e); }
        }

        float4 G4[3];
        float pl = 1.0f;
        #pragma unroll
        for (int k = 0; k < 3; ++k) {
            if (k == 2 && !ok2) continue;
            float4 g;
            g.x = sigf(gl[k].x); g.y = sigf(gl[k].y);
            g.z = sigf(gl[k].z); g.w = sigf(gl[k].w);
            G4[k] = g;
            pl *= fmaf(-2.0f*a4[k].x, g.x, 1.0f);
            pl *= fmaf(-2.0f*a4[k].y, g.y, 1.0f);
            pl *= fmaf(-2.0f*a4[k].z, g.z, 1.0f);
            pl *= fmaf(-2.0f*a4[k].w, g.w, 1.0f);
        }
        float pw = pl;
        #pragma unroll
        for (int off = 1; off < 64; off <<= 1) pw *= __shfl_xor(pw, off, 64);
        __syncthreads();
        if (lane == 0) red[wv] = pw;
        __syncthreads();
        const float p = red[0]*red[1]*red[2]*red[3];
        const float c1pp = c1 * (p + 1.0f);
        const bool pzero = (p == 0.0f);

        float rowl = 0.0f;
        #pragma unroll
        for (int k = 0; k < 3; ++k) {
            if (k == 2 && !ok2) continue;
            const int c4 = tid + 256*k;
            const size_t e = 4*(g4base + c4);
            float4 glo, mo, vo;
            if (pzero) {
                #define COMPF(FLD) { \
                    const float g = G4[k].FLD; \
                    const float d = tu - tv[k].FLD + OEPS; \
                    const float r = fmaxf(d, 0.0f); \
                    const float gg = (c2 * (r*r)) * (g * (1.0f - g)); \
                    const float m2 = fmaf(0.9f, m4[k].FLD, 0.1f*gg); \
                    const float v2 = fmaf(0.999f, v4[k].FLD, 0.001f*gg*gg); \
                    const float den = __fsqrt_rn(v2 * bc2i) + AEPS; \
                    glo.FLD = gl[k].FLD - LRc * (m2 * bc1i) / den; \
                    mo.FLD = m2; vo.FLD = v2; \
                    const float w = g * r; \
                    rowl += w; cacc[k].FLD += w; }
                COMPF(x) COMPF(y) COMPF(z) COMPF(w)
                #undef COMPF
            } else {
                #define COMP(FLD) { \
                    const float g = G4[k].FLD; \
                    const float a = a4[k].FLD; \
                    const float f = fmaf(-2.0f*a, g, 1.0f); \
                    const float po = (f != 0.0f) ? __fdividef(p, f) : 0.0f; \
                    const float d = tu - tv[k].FLD + OEPS; \
                    const float r = fmaxf(d, 0.0f); \
                    const float gg = fmaf(c2, r*r, c1pp * po * (-2.0f*a)) * (g * (1.0f - g)); \
                    const float m2 = fmaf(0.9f, m4[k].FLD, 0.1f*gg); \
                    const float v2 = fmaf(0.999f, v4[k].FLD, 0.001f*gg*gg); \
                    const float den = __fsqrt_rn(v2 * bc2i) + AEPS; \
                    glo.FLD = gl[k].FLD - LRc * (m2 * bc1i) / den; \
                    mo.FLD = m2; vo.FLD = v2; \
                    const float w = g * r; \
                    rowl += w; cacc[k].FLD += w; }
                COMP(x) COMP(y) COMP(z) COMP(w)
                #undef COMP
            }
            st_bf4(GLbf + e, glo);
            st_bf4(mG + e, mo);
            st_bf4(vG + e, vo);
        }

        float sw = rowl;
        #pragma unroll
        for (int off = 1; off < 64; off <<= 1) sw += __shfl_xor(sw, off, 64);
        if (lane == 0) red[4+wv] = sw;
        __syncthreads();
        if (tid == 0) Srow[i] = (red[4]+red[5]) + (red[6]+red[7]);
    }

    float* pc = Pcol + (size_t)b * NT;
    #pragma unroll
    for (int k = 0; k < 3; ++k) {
        if (k == 2 && !ok2) continue;
        *(float4*)(pc + 4*(tid + 256*k)) = cacc[k];
    }
}

template<bool FIRST>
__global__ void __launch_bounds__(TPB)
step_kernel(const float* GLinit, unsigned short* __restrict__ GLbf,
            unsigned short* __restrict__ mG, unsigned short* __restrict__ vG,
            const unsigned short* __restrict__ Abf, const float* __restrict__ tau,
            float* __restrict__ Srow, float* __restrict__ Pcol,
            float bc1i, float bc2i)
{
    __shared__ float red[8];
    step_rows_fb<FIRST>(blockIdx.x, GLinit, GLbf, mG, vG, Abf, tau, Srow, Pcol, bc1i, bc2i, red);
}

__global__ void __launch_bounds__(TPB)
colsum_kernel(const float* __restrict__ Pcol, float* __restrict__ Pcol2)
{
    const int c = blockIdx.x * TPB + threadIdx.x;
    if (c >= NT) return;
    const int s  = blockIdx.y;
    const int r0 = s * RPS;
    const int r1 = (r0 + RPS < NBLK) ? (r0 + RPS) : NBLK;
    float a[4] = {0.f,0.f,0.f,0.f};
    const float* p = Pcol + (size_t)r0 * NT + c;
    int r = r0;
    for (; r + 4 <= r1; r += 4) {
        #pragma unroll
        for (int u = 0; u < 4; ++u) a[u] += p[(size_t)u * NT];
        p += (size_t)4 * NT;
    }
    for (; r < r1; ++r) { a[0] += *p; p += NT; }
    Pcol2[(size_t)s * NT + c] = (a[0]+a[1])+(a[2]+a[3]);
}

template<bool FIRST>
__global__ void __launch_bounds__(TPB)
tau_kernel(const float* tinit, float* tauw,
           float* __restrict__ mt, float* __restrict__ vt,
           const float* __restrict__ Srow, const float* __restrict__ Pcol2,
           float bc1i, float bc2i)
{
    const int k = blockIdx.x * TPB + threadIdx.x;
    if (k >= NALL) return;
    const float ct = 1.0f / ((float)NF * (float)NT);
    float g = 0.0f;
    if (k < NF) g = Srow[k];
    if (k >= 16) {
        const int j = k - 16;
        float s = 0.0f;
        #pragma unroll
        for (int t = 0; t < SPLIT; ++t) s += Pcol2[(size_t)t * NT + j];
        g -= s;
    }
    g *= ct;
    const float t0 = FIRST ? tinit[k] : tauw[k];
    const float m0 = FIRST ? 0.0f : mt[k];
    const float v0 = FIRST ? 0.0f : vt[k];
    const float m2 = fmaf(0.9f, m0, 0.1f*g);
    const float v2 = fmaf(0.999f, v0, 0.001f*g*g);
    const float den = __fsqrt_rn(v2 * bc2i) + AEPS;
    tauw[k] = t0 - LRc * (m2 * bc1i) / den;
    mt[k] = m2; vt[k] = v2;
}

__global__ void __launch_bounds__(TPB)
loss_kernel(const unsigned short* __restrict__ GLbf, const float* __restrict__ A,
            const float* __restrict__ tau, float* __restrict__ out)
{
    __shared__ float red[8];
    const int tid = threadIdx.x;
    const int lane = tid & 63, wv = tid >> 6;
    const bool ok2 = tid < (NC4 - 512);
    const int i = blockIdx.x;
    const float tu = tau[i];
    const size_t g4base = (size_t)i * NC4;
    const size_t abase  = (size_t)i * NALL + 16;
    float pl = 1.0f, sl = 0.0f;
    #pragma unroll
    for (int k = 0; k < 3; ++k) {
        if (k == 2 && !ok2) continue;
        const int c4 = tid + 256*k;
        float4 gl = ld_bf4(GLbf + 4*(g4base + c4));
        float4 a  = *(const float4*)(A + abase + 4*c4);
        float4 tv = *(const float4*)(tau + 16 + 4*c4);
        #define LCOMP(FLD) { \
            const float g = sigf(gl.FLD); \
            pl *= fmaf(-2.0f*a.FLD, g, 1.0f); \
            const float r = fmaxf(tu - tv.FLD + OEPS, 0.0f); \
            sl += g * r * r; }
        LCOMP(x) LCOMP(y) LCOMP(z) LCOMP(w)
        #undef LCOMP
    }
    float pw = pl, sw = sl;
    #pragma unroll
    for (int off = 1; off < 64; off <<= 1) {
        pw *= __shfl_xor(pw, off, 64);
        sw += __shfl_xor(sw, off, 64);
    }
    if (lane == 0) { red[wv] = pw; red[4+wv] = sw; }
    __syncthreads();
    if (tid == 0) {
        const float p = red[0]*red[1]*red[2]*red[3];
        const float s = (red[4]+red[5]) + (red[6]+red[7]);
        const float v = 0.25f*(p+1.0f)*(p+1.0f)*(1.0f/(float)NF)
                      + 0.5f*s*(1.0f/((float)NF*(float)NT));
        atomicAdd(out, v);
    }
}

// ---------------- host ----------------
extern "C" void kernel_launch(void* const* d_in, const int* in_sizes, int n_in,
                              void* d_out, int out_size, void* d_ws, size_t ws_size,
                              hipStream_t stream)
{
    const float* A        = (const float*)d_in[0];
    const float* tau_init = (const float*)d_in[1];
    const float* GL_init  = (const float*)d_in[2];

    const size_t mat = (size_t)NF * NT;
    unsigned short* GLbf = (unsigned short*)d_ws;         // mat bf16
    unsigned short* mGh  = GLbf + mat;                    // mat bf16
    unsigned short* vGh  = mGh + mat;                     // mat bf16
    unsigned short* Abf  = vGh + mat;                     // mat bf16
    float* tau_g  = (float*)(Abf + mat);                  // 2*NALL
    float* mt_g   = tau_g  + 2*NALL;
    float* vt_g   = mt_g   + 2*NALL;
    float* Srow_g = vt_g   + 2*NALL;
    float* Gcol   = Srow_g + 2*NALL;                      // NT
    float* Pcol   = Gcol   + NT;                          // NBLK*NT
    float* Pcol2  = Pcol + (size_t)NBLK * NT;             // SPLIT*NT (fallback)
    float* outp   = (float*)d_out;

    (void)hipMemsetAsync(d_out, 0, (size_t)out_size * sizeof(float), stream);
    castA_kernel<<<NF, TPB, 0, stream>>>(A, Abf);

    int dev = 0, coop = 0, numCU = 0, occ = 0;
    (void)hipGetDevice(&dev);
    (void)hipDeviceGetAttribute(&coop, hipDeviceAttributeCooperativeLaunch, dev);
    (void)hipDeviceGetAttribute(&numCU, hipDeviceAttributeMultiprocessorCount, dev);
    (void)hipOccupancyMaxActiveBlocksPerMultiprocessor(&occ, (const void*)mega_kernel, TPB, 0);

    if (coop && (long)occ * numCU >= NBLK) {
        void* args[] = {
            (void*)&A, (void*)&tau_init, (void*)&GL_init,
            (void*)&GLbf, (void*)&mGh, (void*)&vGh, (void*)&Abf,
            (void*)&tau_g, (void*)&mt_g, (void*)&vt_g,
            (void*)&Srow_g, (void*)&Pcol, (void*)&Gcol, (void*)&outp
        };
        (void)hipLaunchCooperativeKernel((void*)mega_kernel, dim3(NBLK), dim3(TPB),
                                         args, 0, stream);
    } else {
        float* tauw = tau_g;
        float* mt   = mt_g;
        float* vt   = vt_g;
        float* Srow = Srow_g;
        const dim3 csGrid(CGRP, SPLIT);
        for (int it = 1; it <= ITERS; ++it) {
            const float bc1i = (float)(1.0 / (1.0 - pow(0.9,   (double)it)));
            const float bc2i = (float)(1.0 / (1.0 - pow(0.999, (double)it)));
            if (it == 1) {
                step_kernel<true><<<NBLK, TPB, 0, stream>>>(GL_init, GLbf, mGh, vGh, Abf,
                                                            tau_init, Srow, Pcol, bc1i, bc2i);
                colsum_kernel<<<csGrid, TPB, 0, stream>>>(Pcol, Pcol2);
                tau_kernel<true><<<NALL/TPB, TPB, 0, stream>>>(tau_init, tauw, mt, vt,
                                                               Srow, Pcol2, bc1i, bc2i);
            } else {
                step_kernel<false><<<NBLK, TPB, 0, stream>>>(nullptr, GLbf, mGh, vGh, Abf,
                                                             tauw, Srow, Pcol, bc1i, bc2i);
                colsum_kernel<<<csGrid, TPB, 0, stream>>>(Pcol, Pcol2);
                tau_kernel<false><<<NALL/TPB, TPB, 0, stream>>>(nullptr, tauw, mt, vt,
                                                                Srow, Pcol2, bc1i, bc2i);
            }
        }
        loss_kernel<<<NF, TPB, 0, stream>>>(GLbf, A, tauw, (float*)d_out);
    }
}